// Round 11
// baseline (3646.684 us; speedup 1.0000x reference)
//
#include <hip/hip_runtime.h>
#include <math.h>

#define SENT 2.0f
#define NTOK 2048
#define EDIM 512
#define GJ   2048   // 4*HID
#define NW   32     // worker WGs
#define HPW  16     // hidden units per WG
#define LOG2E 1.4426950408889634f

typedef float f32x4 __attribute__((ext_vector_type(4)));

__device__ __forceinline__ float sigm_f(float x) {
  return __builtin_amdgcn_rcpf(1.f + __builtin_amdgcn_exp2f(-LOG2E * x));
}
__device__ __forceinline__ float tanh_f(float x) {
  return 1.f - 2.f * __builtin_amdgcn_rcpf(1.f + __builtin_amdgcn_exp2f(2.f * LOG2E * x));
}

// ---------------- k_init: sentinel fill ----------------
__global__ __launch_bounds__(256) void k_init(float4* __restrict__ H4) {
  int i = blockIdx.x * blockDim.x + threadIdx.x;   // 262144 float4 = 2048*512 floats
  H4[i] = make_float4(SENT, SENT, SENT, SENT);
}

// ---------------- k_compact: stable compaction of selected tokens ----------------
__global__ __launch_bounds__(1024) void k_compact(const float* __restrict__ scores,
                                                  int* __restrict__ sel,
                                                  int* __restrict__ nselp) {
  __shared__ int cnt[1024];
  const int tid = threadIdx.x;
  const int i0 = tid * 2, i1 = tid * 2 + 1;
  const int m0 = (scores[i0] > 0.5f) ? 1 : 0;
  const int m1 = (scores[i1] > 0.5f) ? 1 : 0;
  cnt[tid] = m0 + m1;
  __syncthreads();
  for (int off = 1; off < 1024; off <<= 1) {
    int v = cnt[tid];
    int u = (tid >= off) ? cnt[tid - off] : 0;
    __syncthreads();
    cnt[tid] = v + u;
    __syncthreads();
  }
  int excl = (tid == 0) ? 0 : cnt[tid - 1];
  if (m0) sel[excl] = i0;
  if (m1) sel[excl + m0] = i1;
  if (tid == 1023) *nselp = cnt[1023];
}

// ---------------- k_gemm: C[t][j] = bias1[j](+bias2[j]) + sum_e Arow(t)[e]*B[j][e] ----------------
template<bool GATHER>
__global__ __launch_bounds__(256) void k_gemm(
    const float* __restrict__ A, const float* __restrict__ B,
    const float* __restrict__ bias1, const float* __restrict__ bias2,
    float* __restrict__ C, const int* __restrict__ sel,
    const int* __restrict__ nselp, int J)
{
  const int n_sel = *nselp;
  const int t0 = blockIdx.x * 32;
  if (t0 >= n_sel) return;
  const int j0 = blockIdx.y * 64;
  const int tid = threadIdx.x;
  __shared__ float As[32][36];
  __shared__ float Bst[32][68];
  __shared__ int rowsrc[32];
  if (tid < 32) {
    int t = t0 + tid;
    int r = -1;
    if (t < n_sel) r = GATHER ? sel[t] : t;
    rowsrc[tid] = r;
  }
  __syncthreads();
  const int tx = tid & 15;
  const int ty = tid >> 4;
  float4 acc0 = make_float4(0.f, 0.f, 0.f, 0.f);
  float4 acc1 = make_float4(0.f, 0.f, 0.f, 0.f);
  for (int e0 = 0; e0 < EDIM; e0 += 32) {
    {
      int t = tid >> 3, e4 = tid & 7;
      int r = rowsrc[t];
      float4 v = make_float4(0.f, 0.f, 0.f, 0.f);
      if (r >= 0) v = ((const float4*)(A + (size_t)r * EDIM + e0))[e4];
      *(float4*)&As[t][e4 * 4] = v;
    }
    #pragma unroll
    for (int l = 0; l < 2; ++l) {
      int idx = tid + l * 256;
      int j = idx >> 3, e4 = idx & 7;
      float4 v = ((const float4*)(B + (size_t)(j0 + j) * EDIM + e0))[e4];
      Bst[e4 * 4 + 0][j] = v.x; Bst[e4 * 4 + 1][j] = v.y;
      Bst[e4 * 4 + 2][j] = v.z; Bst[e4 * 4 + 3][j] = v.w;
    }
    __syncthreads();
    #pragma unroll
    for (int e = 0; e < 32; ++e) {
      float a0 = As[ty * 2 + 0][e];
      float a1 = As[ty * 2 + 1][e];
      float4 b = *(const float4*)&Bst[e][tx * 4];
      acc0.x += a0 * b.x; acc0.y += a0 * b.y; acc0.z += a0 * b.z; acc0.w += a0 * b.w;
      acc1.x += a1 * b.x; acc1.y += a1 * b.y; acc1.z += a1 * b.z; acc1.w += a1 * b.w;
    }
    __syncthreads();
  }
  float4 bv = ((const float4*)bias1)[(j0 >> 2) + tx];
  if (bias2) {
    float4 b2 = ((const float4*)bias2)[(j0 >> 2) + tx];
    bv.x += b2.x; bv.y += b2.y; bv.z += b2.z; bv.w += b2.w;
  }
  #pragma unroll
  for (int i = 0; i < 2; ++i) {
    int t = t0 + ty * 2 + i;
    if (t < n_sel) {
      float4 a = (i == 0) ? acc0 : acc1;
      float4 r = make_float4(a.x + bv.x, a.y + bv.y, a.z + bv.z, a.w + bv.w);
      *(float4*)(C + (size_t)t * J + j0 + tx * 4) = r;
    }
  }
}

// ---------------- k_lstm: persistent recurrence, r7 core + clean wave-role split ----------------
// 32 WGs x 640 threads (10 waves), 1/CU. WG w owns units [w*16, w*16+16).
// Waves 0-1 (tid<128): PURE pollers — only vmem = the poll loads (their waitcnt
//   never drains Gin prefetches or h-store acks). Poll = r7's PROVEN asm verbatim
//   (sc0 sc1, 4+4 dwords, 2-deep, single block, drained exits).
// Waves 2-9 (dt=tid-128 >= 0): dot threads, r7 geometry: row=dt>>3, g=row&3,
//   u=row>>2; unit u = 32 consecutive lanes of one wave; gate lane dt%32==0 does
//   Gin prefetch + gates + agent h-store and NEVER polls.
// Weights: r7 handling (plain C global loads; compiler pipelines L2 reloads —
//   measured faster than both pinned-VGPR (r9 scratch spill) and LDS (r10 8-way
//   bank conflict)). One barrier/step; hbuf parity ping-pong.
__global__ __launch_bounds__(640, 1) void k_lstm(
    const float* __restrict__ Gin, float* __restrict__ Hout,
    const float* __restrict__ Whh, const int* __restrict__ nselp)
{
  const int tid = threadIdx.x;
  const int n_sel = *nselp;
  if (n_sel <= 0) return;
  const int w = blockIdx.x;

  // ---- dot-thread geometry (r7) ----
  const int dt = tid - 128;              // dot-thread index 0..511 (neg = poller)
  const int row_local = dt >> 3;         // 0..63
  const int sub = dt & 7;
  const int g = row_local & 3;           // gate 0..3 (i,f,g,o)
  const int jl = row_local >> 2;         // unit within slice
  const int c0 = sub * 64;
  const int grow = g * 512 + w * HPW + jl;

  float4 wv[16];
  if (dt >= 0) {
    const float4* wp = (const float4*)(Whh + (size_t)grow * 512 + c0);
    #pragma unroll
    for (int k = 0; k < 16; ++k) wv[k] = wp[(k + sub) & 15];
  }

  // ---- roles ----
  const int q = (tid < 128) ? tid : -1;                    // poller quad
  const bool pact = (q >= 0) && (q < 4 * w || q >= 4 * w + 4);
  const bool gatel = (dt >= 0) && ((dt & 31) == 0);        // gate lane, unit u
  const int u = dt >> 5;

  __shared__ float hbuf[2][512];
  if (tid < 512) hbuf[0][tid] = 0.f;     // h(-1) = 0 (ordered by iter-0 barrier)
  float cst = 0.f;
  float gx0 = 0.f, gx1 = 0.f, gx2 = 0.f, gx3 = 0.f;
  if (gatel) {
    const float* gr = Gin + w * HPW + u;
    gx0 = gr[0]; gx1 = gr[512]; gx2 = gr[1024]; gx3 = gr[1536];
  }
  for (int t = 0; t < n_sel; ++t) {
    const int cur = t & 1;
    float nx0 = 0.f, nx1 = 0.f, nx2 = 0.f, nx3 = 0.f;
    if (gatel && t + 1 < n_sel) {
      const float* gr = Gin + (size_t)(t + 1) * GJ + w * HPW + u;
      nx0 = gr[0]; nx1 = gr[512]; nx2 = gr[1024]; nx3 = gr[1536];
    }
    if (t > 0 && pact) {
      const float* src = Hout + (size_t)(t - 1) * 512 + q * 4;
      float a0, a1, a2, a3, b0, b1, b2, b3, m;
      // r7-proven poll: 2-deep pipelined, ENTIRELY in one asm block
      asm volatile(
        "global_load_dword %[a0], %[s], off sc0 sc1\n\t"
        "global_load_dword %[a1], %[s], off offset:4 sc0 sc1\n\t"
        "global_load_dword %[a2], %[s], off offset:8 sc0 sc1\n\t"
        "global_load_dword %[a3], %[s], off offset:12 sc0 sc1\n\t"
        "global_load_dword %[b0], %[s], off sc0 sc1\n\t"
        "global_load_dword %[b1], %[s], off offset:4 sc0 sc1\n\t"
        "global_load_dword %[b2], %[s], off offset:8 sc0 sc1\n\t"
        "global_load_dword %[b3], %[s], off offset:12 sc0 sc1\n\t"
        "PL%=:\n\t"
        "s_waitcnt vmcnt(4)\n\t"                      // batch A landed
        "v_max3_f32 %[m], %[a0], %[a1], %[a2]\n\t"
        "v_max_f32 %[m], %[m], %[a3]\n\t"
        "v_cmp_lt_f32 vcc, 1.5, %[m]\n\t"             // lane still-sentinel?
        "s_cbranch_vccz GA%=\n\t"                     // no lane sentinel -> A valid
        "global_load_dword %[a0], %[s], off sc0 sc1\n\t"
        "global_load_dword %[a1], %[s], off offset:4 sc0 sc1\n\t"
        "global_load_dword %[a2], %[s], off offset:8 sc0 sc1\n\t"
        "global_load_dword %[a3], %[s], off offset:12 sc0 sc1\n\t"
        "s_waitcnt vmcnt(4)\n\t"                      // batch B landed
        "v_max3_f32 %[m], %[b0], %[b1], %[b2]\n\t"
        "v_max_f32 %[m], %[m], %[b3]\n\t"
        "v_cmp_lt_f32 vcc, 1.5, %[m]\n\t"
        "s_cbranch_vccz GB%=\n\t"
        "global_load_dword %[b0], %[s], off sc0 sc1\n\t"
        "global_load_dword %[b1], %[s], off offset:4 sc0 sc1\n\t"
        "global_load_dword %[b2], %[s], off offset:8 sc0 sc1\n\t"
        "global_load_dword %[b3], %[s], off offset:12 sc0 sc1\n\t"
        "s_branch PL%=\n\t"
        "GB%=:\n\t"
        "s_waitcnt vmcnt(0)\n\t"                      // stale in-flight A lands first
        "v_mov_b32 %[a0], %[b0]\n\t"
        "v_mov_b32 %[a1], %[b1]\n\t"
        "v_mov_b32 %[a2], %[b2]\n\t"
        "v_mov_b32 %[a3], %[b3]\n\t"
        "GA%=:\n\t"
        "s_waitcnt vmcnt(0)\n\t"                      // drain leftover B (discard)
        : [a0]"=&v"(a0), [a1]"=&v"(a1), [a2]"=&v"(a2), [a3]"=&v"(a3),
          [b0]"=&v"(b0), [b1]"=&v"(b1), [b2]"=&v"(b2), [b3]"=&v"(b3),
          [m]"=&v"(m)
        : [s]"v"(src)
        : "vcc", "memory");
      hbuf[cur][q * 4 + 0] = a0; hbuf[cur][q * 4 + 1] = a1;
      hbuf[cur][q * 4 + 2] = a2; hbuf[cur][q * 4 + 3] = a3;
    }
    __syncthreads();   // the ONLY barrier per step
    if (dt >= 0) {
      // partial dot over 64 cols, sub-rotated, 4 accumulators (r7)
      const float4* hv = (const float4*)&hbuf[cur][c0];
      float s0 = 0.f, s1 = 0.f, s2 = 0.f, s3 = 0.f;
      #pragma unroll
      for (int k = 0; k < 4; ++k) {
        float4 w4, h4;
        w4 = wv[4*k+0]; h4 = hv[(4*k+0+sub)&15]; s0 += w4.x*h4.x + w4.y*h4.y + w4.z*h4.z + w4.w*h4.w;
        w4 = wv[4*k+1]; h4 = hv[(4*k+1+sub)&15]; s1 += w4.x*h4.x + w4.y*h4.y + w4.z*h4.z + w4.w*h4.w;
        w4 = wv[4*k+2]; h4 = hv[(4*k+2+sub)&15]; s2 += w4.x*h4.x + w4.y*h4.y + w4.z*h4.z + w4.w*h4.w;
        w4 = wv[4*k+3]; h4 = hv[(4*k+3+sub)&15]; s3 += w4.x*h4.x + w4.y*h4.y + w4.z*h4.z + w4.w*h4.w;
      }
      float s = (s0 + s1) + (s2 + s3);
      s += __shfl_xor(s, 1); s += __shfl_xor(s, 2); s += __shfl_xor(s, 4);
      // hand f/g/o row sums to the unit's gate lane (same wave by construction)
      const int lane = dt & 63;
      float sf = __shfl(s, lane + 8);
      float sg = __shfl(s, lane + 16);
      float so = __shfl(s, lane + 24);
      if (gatel) {
        float gi = gx0 + s;
        float gf = gx1 + sf;
        float gg = gx2 + sg;
        float go = gx3 + so;
        float ig = sigm_f(gi);
        float fg = sigm_f(gf);
        float og = sigm_f(go);
        cst = fg * cst + ig * tanh_f(gg);
        float h = og * tanh_f(cst);   // in (-1,1): sentinel 2.0f unreachable
        __hip_atomic_store(Hout + (size_t)t * 512 + w * HPW + u, h,
                           __ATOMIC_RELAXED, __HIP_MEMORY_SCOPE_AGENT);
        hbuf[cur ^ 1][w * HPW + u] = h;   // next step's buffer: no reader overlap
        gx0 = nx0; gx1 = nx1; gx2 = nx2; gx3 = nx3;
      }
    }
  }
}

// ---------------- k_norms: row L2 norms (memory keys + queries) ----------------
__global__ __launch_bounds__(256) void k_norms(
    const float* __restrict__ memo, const float* __restrict__ qe,
    float* __restrict__ dens, const int* __restrict__ nselp)
{
  const int n_sel = *nselp;
  const int row = blockIdx.x * 4 + (threadIdx.x >> 6);
  const int lane = threadIdx.x & 63;
  const float* src;
  if (row < NTOK) {
    if (row >= n_sel) return;
    src = memo + (size_t)row * EDIM;
  } else {
    if (row >= NTOK + 256) return;
    src = qe + (size_t)(row - NTOK) * EDIM;
  }
  const float4* s4 = (const float4*)src;
  float4 a = s4[lane], b = s4[lane + 64];
  float s = a.x*a.x + a.y*a.y + a.z*a.z + a.w*a.w
          + b.x*b.x + b.y*b.y + b.z*b.z + b.w*b.w;
  #pragma unroll
  for (int off = 32; off; off >>= 1) s += __shfl_xor(s, off);
  if (lane == 0) dens[row] = fmaxf(sqrtf(s), 1e-12f);
}

// ---------------- k_retrieve: sims + top-k + gather (4 queries per block) ----------------
__global__ __launch_bounds__(256) void k_retrieve(
    const float* __restrict__ memo, const float* __restrict__ qe,
    const float* __restrict__ dens, const float* __restrict__ values,
    const int* __restrict__ sel, const int* __restrict__ nselp,
    float* __restrict__ out, int top_k)
{
  const int n_sel = *nselp;
  const int qb = blockIdx.x * 4;
  const int tid = threadIdx.x;
  __shared__ float qs[4][EDIM];
  __shared__ float sims[4][NTOK];
  __shared__ int tix[4][8];
  for (int l = tid; l < 512; l += 256) {
    int q = l >> 7, e4 = l & 127;
    float4 v = ((const float4*)(qe + (size_t)(qb + q) * EDIM))[e4];
    float inv = 1.f / dens[NTOK + qb + q];
    v.x *= inv; v.y *= inv; v.z *= inv; v.w *= inv;
    *(float4*)&qs[q][e4 * 4] = v;
  }
  __syncthreads();
  for (int t = tid; t < n_sel; t += 256) {
    const float4* m4 = (const float4*)(memo + (size_t)t * EDIM);
    float a0 = 0.f, a1 = 0.f, a2 = 0.f, a3 = 0.f;
    for (int e4 = 0; e4 < 128; ++e4) {
      float4 m = m4[e4];
      float4 q0 = *(const float4*)&qs[0][e4 * 4];
      float4 q1 = *(const float4*)&qs[1][e4 * 4];
      float4 q2 = *(const float4*)&qs[2][e4 * 4];
      float4 q3 = *(const float4*)&qs[3][e4 * 4];
      a0 += m.x*q0.x + m.y*q0.y + m.z*q0.z + m.w*q0.w;
      a1 += m.x*q1.x + m.y*q1.y + m.z*q1.z + m.w*q1.w;
      a2 += m.x*q2.x + m.y*q2.y + m.z*q2.z + m.w*q2.w;
      a3 += m.x*q3.x + m.y*q3.y + m.z*q3.z + m.w*q3.w;
    }
    float inv = 1.f / dens[t];
    sims[0][t] = a0 * inv; sims[1][t] = a1 * inv;
    sims[2][t] = a2 * inv; sims[3][t] = a3 * inv;
  }
  __syncthreads();
  const int wq = tid >> 6, lane = tid & 63;
  for (int r = 0; r < top_k; ++r) {
    if (r < n_sel) {
      float bv = -INFINITY; int bi = 0x7fffffff;
      for (int t = lane; t < n_sel; t += 64) {
        float v = sims[wq][t];
        if (v > bv || (v == bv && t < bi)) { bv = v; bi = t; }
      }
      #pragma unroll
      for (int off = 32; off; off >>= 1) {
        float ov = __shfl_xor(bv, off);
        int   oi = __shfl_xor(bi, off);
        if (ov > bv || (ov == bv && oi < bi)) { bv = ov; bi = oi; }
      }
      if (lane == 0) { tix[wq][r] = bi; sims[wq][bi] = -INFINITY; }
    } else if (lane == 0) {
      tix[wq][r] = -1;
    }
    __syncthreads();
  }
  const int tot = 4 * top_k * 128;
  for (int l = tid; l < tot; l += 256) {
    int q = l / (top_k * 128);
    int rem = l - q * top_k * 128;
    int r = rem >> 7;
    int e4 = rem & 127;
    int t = tix[q][r];
    float4 v = make_float4(0.f, 0.f, 0.f, 0.f);
    if (t >= 0) v = ((const float4*)(values + (size_t)sel[t] * EDIM))[e4];
    ((float4*)out)[(((size_t)(qb + q) * top_k) + r) * 128 + e4] = v;
  }
}

extern "C" void kernel_launch(void* const* d_in, const int* in_sizes, int n_in,
                              void* d_out, int out_size, void* d_ws, size_t ws_size,
                              hipStream_t stream) {
  const float* keys   = (const float*)d_in[0];
  const float* values = (const float*)d_in[1];
  const float* scores = (const float*)d_in[2];
  const float* qe     = (const float*)d_in[3];
  const float* W_ih   = (const float*)d_in[6];
  const float* W_hh   = (const float*)d_in[7];
  const float* b_ih   = (const float*)d_in[8];
  const float* b_hh   = (const float*)d_in[9];
  const float* W_out  = (const float*)d_in[10];
  const float* b_out  = (const float*)d_in[11];
  float* out = (float*)d_out;
  const int top_k = out_size / (256 * 512);   // = 8

  char* ws = (char*)d_ws;
  int*   nsel   = (int*)ws;                             // 4 B
  int*   sel    = (int*)(ws + 4096);                    // 8 KB
  float* dens   = (float*)(ws + 16384);                 // 9 KB
  float* Hout   = (float*)(ws + (size_t)(1u << 20));    // 4 MB  [1M,5M)
  float* Gin    = (float*)(ws + (size_t)(9u << 20));    // 16 MB [9M,25M)
  float* memo   = (float*)(ws + (size_t)(9u << 20));    // 4 MB, aliases Gin (dead by then)
  (void)in_sizes; (void)n_in; (void)ws_size;

  k_init<<<1024, 256, 0, stream>>>((float4*)Hout);
  k_compact<<<1, 1024, 0, stream>>>(scores, sel, nsel);
  k_gemm<true ><<<dim3(64, 32), 256, 0, stream>>>(keys, W_ih, b_ih, b_hh, Gin, sel, nsel, GJ);
  k_lstm<<<NW, 640, 0, stream>>>(Gin, Hout, W_hh, nsel);
  k_gemm<false><<<dim3(64, 8), 256, 0, stream>>>(Hout, W_out, b_out, nullptr, memo, nullptr, nsel, EDIM);
  k_norms<<<576, 256, 0, stream>>>(memo, qe, dens, nsel);
  k_retrieve<<<64, 256, 0, stream>>>(memo, qe, dens, values, sel, nsel, out, top_k);
}

// Round 12
// 2147.240 us; speedup vs baseline: 1.6983x; 1.6983x over previous
//
#include <hip/hip_runtime.h>
#include <math.h>

#define SENT 2.0f
#define NTOK 2048
#define EDIM 512
#define GJ   2048   // 4*HID
#define NW   32     // worker WGs
#define HPW  16     // hidden units per WG
#define LOG2E 1.4426950408889634f

typedef float f32x4 __attribute__((ext_vector_type(4)));

__device__ __forceinline__ float sigm_f(float x) {
  return __builtin_amdgcn_rcpf(1.f + __builtin_amdgcn_exp2f(-LOG2E * x));
}
__device__ __forceinline__ float tanh_f(float x) {
  return 1.f - 2.f * __builtin_amdgcn_rcpf(1.f + __builtin_amdgcn_exp2f(2.f * LOG2E * x));
}

// ---------------- k_init: sentinel fill ----------------
__global__ __launch_bounds__(256) void k_init(float4* __restrict__ H4) {
  int i = blockIdx.x * blockDim.x + threadIdx.x;   // 262144 float4 = 2048*512 floats
  H4[i] = make_float4(SENT, SENT, SENT, SENT);
}

// ---------------- k_compact: stable compaction of selected tokens ----------------
__global__ __launch_bounds__(1024) void k_compact(const float* __restrict__ scores,
                                                  int* __restrict__ sel,
                                                  int* __restrict__ nselp) {
  __shared__ int cnt[1024];
  const int tid = threadIdx.x;
  const int i0 = tid * 2, i1 = tid * 2 + 1;
  const int m0 = (scores[i0] > 0.5f) ? 1 : 0;
  const int m1 = (scores[i1] > 0.5f) ? 1 : 0;
  cnt[tid] = m0 + m1;
  __syncthreads();
  for (int off = 1; off < 1024; off <<= 1) {
    int v = cnt[tid];
    int u = (tid >= off) ? cnt[tid - off] : 0;
    __syncthreads();
    cnt[tid] = v + u;
    __syncthreads();
  }
  int excl = (tid == 0) ? 0 : cnt[tid - 1];
  if (m0) sel[excl] = i0;
  if (m1) sel[excl + m0] = i1;
  if (tid == 1023) *nselp = cnt[1023];
}

// ---------------- k_gemm: C[t][j] = bias1[j](+bias2[j]) + sum_e Arow(t)[e]*B[j][e] ----------------
template<bool GATHER>
__global__ __launch_bounds__(256) void k_gemm(
    const float* __restrict__ A, const float* __restrict__ B,
    const float* __restrict__ bias1, const float* __restrict__ bias2,
    float* __restrict__ C, const int* __restrict__ sel,
    const int* __restrict__ nselp, int J)
{
  const int n_sel = *nselp;
  const int t0 = blockIdx.x * 32;
  if (t0 >= n_sel) return;
  const int j0 = blockIdx.y * 64;
  const int tid = threadIdx.x;
  __shared__ float As[32][36];
  __shared__ float Bst[32][68];
  __shared__ int rowsrc[32];
  if (tid < 32) {
    int t = t0 + tid;
    int r = -1;
    if (t < n_sel) r = GATHER ? sel[t] : t;
    rowsrc[tid] = r;
  }
  __syncthreads();
  const int tx = tid & 15;
  const int ty = tid >> 4;
  float4 acc0 = make_float4(0.f, 0.f, 0.f, 0.f);
  float4 acc1 = make_float4(0.f, 0.f, 0.f, 0.f);
  for (int e0 = 0; e0 < EDIM; e0 += 32) {
    {
      int t = tid >> 3, e4 = tid & 7;
      int r = rowsrc[t];
      float4 v = make_float4(0.f, 0.f, 0.f, 0.f);
      if (r >= 0) v = ((const float4*)(A + (size_t)r * EDIM + e0))[e4];
      *(float4*)&As[t][e4 * 4] = v;
    }
    #pragma unroll
    for (int l = 0; l < 2; ++l) {
      int idx = tid + l * 256;
      int j = idx >> 3, e4 = idx & 7;
      float4 v = ((const float4*)(B + (size_t)(j0 + j) * EDIM + e0))[e4];
      Bst[e4 * 4 + 0][j] = v.x; Bst[e4 * 4 + 1][j] = v.y;
      Bst[e4 * 4 + 2][j] = v.z; Bst[e4 * 4 + 3][j] = v.w;
    }
    __syncthreads();
    #pragma unroll
    for (int e = 0; e < 32; ++e) {
      float a0 = As[ty * 2 + 0][e];
      float a1 = As[ty * 2 + 1][e];
      float4 b = *(const float4*)&Bst[e][tx * 4];
      acc0.x += a0 * b.x; acc0.y += a0 * b.y; acc0.z += a0 * b.z; acc0.w += a0 * b.w;
      acc1.x += a1 * b.x; acc1.y += a1 * b.y; acc1.z += a1 * b.z; acc1.w += a1 * b.w;
    }
    __syncthreads();
  }
  float4 bv = ((const float4*)bias1)[(j0 >> 2) + tx];
  if (bias2) {
    float4 b2 = ((const float4*)bias2)[(j0 >> 2) + tx];
    bv.x += b2.x; bv.y += b2.y; bv.z += b2.z; bv.w += b2.w;
  }
  #pragma unroll
  for (int i = 0; i < 2; ++i) {
    int t = t0 + ty * 2 + i;
    if (t < n_sel) {
      float4 a = (i == 0) ? acc0 : acc1;
      float4 r = make_float4(a.x + bv.x, a.y + bv.y, a.z + bv.z, a.w + bv.w);
      *(float4*)(C + (size_t)t * J + j0 + tx * 4) = r;
    }
  }
}

// ---------------- k_lstm: r7 champion + poll-before-prefetch reorder ----------------
// EXACT r7 structure (proven 1630us, absmax 0): 32 WGs x 512 threads, 1/CU;
// pollers = odd tids <256 (r7 asm verbatim: sc0 sc1, 2-deep, ONE block);
// gate lanes tid%32==0; one barrier/step; hbuf parity; shuffle gate handoff.
// ONE change: poll block now comes BEFORE the Gin prefetch block. In r7 the
// gate lanes (lanes 0/32 of the SAME waves as pollers) issued 4 L3 Gin loads
// before the poll asm; vmcnt retires in issue order, so the poll's vmcnt(4)
// drained them (~400-700cy) on the critical path EVERY step. Reordered, Gin
// loads retire in the dot's shadow. (r11 lesson: keep pollers = dot threads —
// eager pure-poller waves storm L3 and double step time.)
__global__ __launch_bounds__(512, 1) void k_lstm(
    const float* __restrict__ Gin, float* __restrict__ Hout,
    const float* __restrict__ Whh, const int* __restrict__ nselp)
{
  const int tid = threadIdx.x;
  const int n_sel = *nselp;
  if (n_sel <= 0) return;
  const int w = blockIdx.x;

  const int row_local = tid >> 3;        // 0..63
  const int sub = tid & 7;
  const int g = row_local & 3;           // gate 0..3 (i,f,g,o)
  const int jl = row_local >> 2;         // unit within slice
  const int grow = g * 512 + w * HPW + jl;
  const int c0 = sub * 64;
  float4 wv[16];
  {
    const float4* wp = (const float4*)(Whh + (size_t)grow * 512 + c0);
    #pragma unroll
    for (int k = 0; k < 16; ++k) wv[k] = wp[(k + sub) & 15];
  }

  // roles (r7): pollers = odd tids < 256; gate lane = tid%32==0 (unit u=tid>>5)
  const bool gatel = (tid & 31) == 0;
  const int u = tid >> 5;
  const bool pol = (tid & 1) && (tid < 256);
  const int q = pol ? ((tid - 1) >> 1) : -1;
  const bool pact = pol && (q < 4 * w || q >= 4 * w + 4);

  __shared__ float hbuf[2][512];
  hbuf[0][tid] = 0.f;                    // h(-1) = 0 (ordered by iter-0 barrier)
  float cst = 0.f;
  float gx0 = 0.f, gx1 = 0.f, gx2 = 0.f, gx3 = 0.f;
  if (gatel) {
    const float* gr = Gin + w * HPW + u;
    gx0 = gr[0]; gx1 = gr[512]; gx2 = gr[1024]; gx3 = gr[1536];
  }
  for (int t = 0; t < n_sel; ++t) {
    const int cur = t & 1;
    // ---- poll FIRST (no Gin loads ahead of it in this iteration's vmcnt) ----
    if (t > 0 && pact) {
      const float* src = Hout + (size_t)(t - 1) * 512 + q * 4;
      float a0, a1, a2, a3, b0, b1, b2, b3, m;
      // r7-proven poll: 2-deep pipelined, ENTIRELY in one asm block
      asm volatile(
        "global_load_dword %[a0], %[s], off sc0 sc1\n\t"
        "global_load_dword %[a1], %[s], off offset:4 sc0 sc1\n\t"
        "global_load_dword %[a2], %[s], off offset:8 sc0 sc1\n\t"
        "global_load_dword %[a3], %[s], off offset:12 sc0 sc1\n\t"
        "global_load_dword %[b0], %[s], off sc0 sc1\n\t"
        "global_load_dword %[b1], %[s], off offset:4 sc0 sc1\n\t"
        "global_load_dword %[b2], %[s], off offset:8 sc0 sc1\n\t"
        "global_load_dword %[b3], %[s], off offset:12 sc0 sc1\n\t"
        "PL%=:\n\t"
        "s_waitcnt vmcnt(4)\n\t"                      // batch A landed
        "v_max3_f32 %[m], %[a0], %[a1], %[a2]\n\t"
        "v_max_f32 %[m], %[m], %[a3]\n\t"
        "v_cmp_lt_f32 vcc, 1.5, %[m]\n\t"             // lane still-sentinel?
        "s_cbranch_vccz GA%=\n\t"                     // no lane sentinel -> A valid
        "global_load_dword %[a0], %[s], off sc0 sc1\n\t"
        "global_load_dword %[a1], %[s], off offset:4 sc0 sc1\n\t"
        "global_load_dword %[a2], %[s], off offset:8 sc0 sc1\n\t"
        "global_load_dword %[a3], %[s], off offset:12 sc0 sc1\n\t"
        "s_waitcnt vmcnt(4)\n\t"                      // batch B landed
        "v_max3_f32 %[m], %[b0], %[b1], %[b2]\n\t"
        "v_max_f32 %[m], %[m], %[b3]\n\t"
        "v_cmp_lt_f32 vcc, 1.5, %[m]\n\t"
        "s_cbranch_vccz GB%=\n\t"
        "global_load_dword %[b0], %[s], off sc0 sc1\n\t"
        "global_load_dword %[b1], %[s], off offset:4 sc0 sc1\n\t"
        "global_load_dword %[b2], %[s], off offset:8 sc0 sc1\n\t"
        "global_load_dword %[b3], %[s], off offset:12 sc0 sc1\n\t"
        "s_branch PL%=\n\t"
        "GB%=:\n\t"
        "s_waitcnt vmcnt(0)\n\t"                      // stale in-flight A lands first
        "v_mov_b32 %[a0], %[b0]\n\t"
        "v_mov_b32 %[a1], %[b1]\n\t"
        "v_mov_b32 %[a2], %[b2]\n\t"
        "v_mov_b32 %[a3], %[b3]\n\t"
        "GA%=:\n\t"
        "s_waitcnt vmcnt(0)\n\t"                      // drain leftovers (reg-reuse safety)
        : [a0]"=&v"(a0), [a1]"=&v"(a1), [a2]"=&v"(a2), [a3]"=&v"(a3),
          [b0]"=&v"(b0), [b1]"=&v"(b1), [b2]"=&v"(b2), [b3]"=&v"(b3),
          [m]"=&v"(m)
        : [s]"v"(src)
        : "vcc", "memory");
      hbuf[cur][q * 4 + 0] = a0; hbuf[cur][q * 4 + 1] = a1;
      hbuf[cur][q * 4 + 2] = a2; hbuf[cur][q * 4 + 3] = a3;
    }
    // ---- Gin prefetch AFTER poll: retires in the dot's shadow ----
    float nx0 = 0.f, nx1 = 0.f, nx2 = 0.f, nx3 = 0.f;
    if (gatel && t + 1 < n_sel) {
      const float* gr = Gin + (size_t)(t + 1) * GJ + w * HPW + u;
      nx0 = gr[0]; nx1 = gr[512]; nx2 = gr[1024]; nx3 = gr[1536];
    }
    __syncthreads();   // the ONLY barrier per step
    // partial dot over 64 cols, sub-rotated, 4 accumulators
    const float4* hv = (const float4*)&hbuf[cur][c0];
    float s0 = 0.f, s1 = 0.f, s2 = 0.f, s3 = 0.f;
    #pragma unroll
    for (int k = 0; k < 4; ++k) {
      float4 w4, h4;
      w4 = wv[4*k+0]; h4 = hv[(4*k+0+sub)&15]; s0 += w4.x*h4.x + w4.y*h4.y + w4.z*h4.z + w4.w*h4.w;
      w4 = wv[4*k+1]; h4 = hv[(4*k+1+sub)&15]; s1 += w4.x*h4.x + w4.y*h4.y + w4.z*h4.z + w4.w*h4.w;
      w4 = wv[4*k+2]; h4 = hv[(4*k+2+sub)&15]; s2 += w4.x*h4.x + w4.y*h4.y + w4.z*h4.z + w4.w*h4.w;
      w4 = wv[4*k+3]; h4 = hv[(4*k+3+sub)&15]; s3 += w4.x*h4.x + w4.y*h4.y + w4.z*h4.z + w4.w*h4.w;
    }
    float s = (s0 + s1) + (s2 + s3);
    s += __shfl_xor(s, 1); s += __shfl_xor(s, 2); s += __shfl_xor(s, 4);
    // hand f/g/o row sums to the gate lane of each unit (same wave by construction)
    const int lane = tid & 63;
    float sf = __shfl(s, lane + 8);
    float sg = __shfl(s, lane + 16);
    float so = __shfl(s, lane + 24);
    if (gatel) {
      float gi = gx0 + s;
      float gf = gx1 + sf;
      float gg = gx2 + sg;
      float go = gx3 + so;
      float ig = sigm_f(gi);
      float fg = sigm_f(gf);
      float og = sigm_f(go);
      cst = fg * cst + ig * tanh_f(gg);
      float h = og * tanh_f(cst);   // in (-1,1): sentinel 2.0f unreachable
      __hip_atomic_store(Hout + (size_t)t * 512 + w * HPW + u, h,
                         __ATOMIC_RELAXED, __HIP_MEMORY_SCOPE_AGENT);
      hbuf[cur ^ 1][w * HPW + u] = h;   // next step's buffer: no reader overlap
      gx0 = nx0; gx1 = nx1; gx2 = nx2; gx3 = nx3;
    }
  }
}

// ---------------- k_norms: row L2 norms (memory keys + queries) ----------------
__global__ __launch_bounds__(256) void k_norms(
    const float* __restrict__ memo, const float* __restrict__ qe,
    float* __restrict__ dens, const int* __restrict__ nselp)
{
  const int n_sel = *nselp;
  const int row = blockIdx.x * 4 + (threadIdx.x >> 6);
  const int lane = threadIdx.x & 63;
  const float* src;
  if (row < NTOK) {
    if (row >= n_sel) return;
    src = memo + (size_t)row * EDIM;
  } else {
    if (row >= NTOK + 256) return;
    src = qe + (size_t)(row - NTOK) * EDIM;
  }
  const float4* s4 = (const float4*)src;
  float4 a = s4[lane], b = s4[lane + 64];
  float s = a.x*a.x + a.y*a.y + a.z*a.z + a.w*a.w
          + b.x*b.x + b.y*b.y + b.z*b.z + b.w*b.w;
  #pragma unroll
  for (int off = 32; off; off >>= 1) s += __shfl_xor(s, off);
  if (lane == 0) dens[row] = fmaxf(sqrtf(s), 1e-12f);
}

// ---------------- k_retrieve: sims + top-k + gather (4 queries per block) ----------------
__global__ __launch_bounds__(256) void k_retrieve(
    const float* __restrict__ memo, const float* __restrict__ qe,
    const float* __restrict__ dens, const float* __restrict__ values,
    const int* __restrict__ sel, const int* __restrict__ nselp,
    float* __restrict__ out, int top_k)
{
  const int n_sel = *nselp;
  const int qb = blockIdx.x * 4;
  const int tid = threadIdx.x;
  __shared__ float qs[4][EDIM];
  __shared__ float sims[4][NTOK];
  __shared__ int tix[4][8];
  for (int l = tid; l < 512; l += 256) {
    int q = l >> 7, e4 = l & 127;
    float4 v = ((const float4*)(qe + (size_t)(qb + q) * EDIM))[e4];
    float inv = 1.f / dens[NTOK + qb + q];
    v.x *= inv; v.y *= inv; v.z *= inv; v.w *= inv;
    *(float4*)&qs[q][e4 * 4] = v;
  }
  __syncthreads();
  for (int t = tid; t < n_sel; t += 256) {
    const float4* m4 = (const float4*)(memo + (size_t)t * EDIM);
    float a0 = 0.f, a1 = 0.f, a2 = 0.f, a3 = 0.f;
    for (int e4 = 0; e4 < 128; ++e4) {
      float4 m = m4[e4];
      float4 q0 = *(const float4*)&qs[0][e4 * 4];
      float4 q1 = *(const float4*)&qs[1][e4 * 4];
      float4 q2 = *(const float4*)&qs[2][e4 * 4];
      float4 q3 = *(const float4*)&qs[3][e4 * 4];
      a0 += m.x*q0.x + m.y*q0.y + m.z*q0.z + m.w*q0.w;
      a1 += m.x*q1.x + m.y*q1.y + m.z*q1.z + m.w*q1.w;
      a2 += m.x*q2.x + m.y*q2.y + m.z*q2.z + m.w*q2.w;
      a3 += m.x*q3.x + m.y*q3.y + m.z*q3.z + m.w*q3.w;
    }
    float inv = 1.f / dens[t];
    sims[0][t] = a0 * inv; sims[1][t] = a1 * inv;
    sims[2][t] = a2 * inv; sims[3][t] = a3 * inv;
  }
  __syncthreads();
  const int wq = tid >> 6, lane = tid & 63;
  for (int r = 0; r < top_k; ++r) {
    if (r < n_sel) {
      float bv = -INFINITY; int bi = 0x7fffffff;
      for (int t = lane; t < n_sel; t += 64) {
        float v = sims[wq][t];
        if (v > bv || (v == bv && t < bi)) { bv = v; bi = t; }
      }
      #pragma unroll
      for (int off = 32; off; off >>= 1) {
        float ov = __shfl_xor(bv, off);
        int   oi = __shfl_xor(bi, off);
        if (ov > bv || (ov == bv && oi < bi)) { bv = ov; bi = oi; }
      }
      if (lane == 0) { tix[wq][r] = bi; sims[wq][bi] = -INFINITY; }
    } else if (lane == 0) {
      tix[wq][r] = -1;
    }
    __syncthreads();
  }
  const int tot = 4 * top_k * 128;
  for (int l = tid; l < tot; l += 256) {
    int q = l / (top_k * 128);
    int rem = l - q * top_k * 128;
    int r = rem >> 7;
    int e4 = rem & 127;
    int t = tix[q][r];
    float4 v = make_float4(0.f, 0.f, 0.f, 0.f);
    if (t >= 0) v = ((const float4*)(values + (size_t)sel[t] * EDIM))[e4];
    ((float4*)out)[(((size_t)(qb + q) * top_k) + r) * 128 + e4] = v;
  }
}

extern "C" void kernel_launch(void* const* d_in, const int* in_sizes, int n_in,
                              void* d_out, int out_size, void* d_ws, size_t ws_size,
                              hipStream_t stream) {
  const float* keys   = (const float*)d_in[0];
  const float* values = (const float*)d_in[1];
  const float* scores = (const float*)d_in[2];
  const float* qe     = (const float*)d_in[3];
  const float* W_ih   = (const float*)d_in[6];
  const float* W_hh   = (const float*)d_in[7];
  const float* b_ih   = (const float*)d_in[8];
  const float* b_hh   = (const float*)d_in[9];
  const float* W_out  = (const float*)d_in[10];
  const float* b_out  = (const float*)d_in[11];
  float* out = (float*)d_out;
  const int top_k = out_size / (256 * 512);   // = 8

  char* ws = (char*)d_ws;
  int*   nsel   = (int*)ws;                             // 4 B
  int*   sel    = (int*)(ws + 4096);                    // 8 KB
  float* dens   = (float*)(ws + 16384);                 // 9 KB
  float* Hout   = (float*)(ws + (size_t)(1u << 20));    // 4 MB  [1M,5M)
  float* Gin    = (float*)(ws + (size_t)(9u << 20));    // 16 MB [9M,25M)
  float* memo   = (float*)(ws + (size_t)(9u << 20));    // 4 MB, aliases Gin (dead by then)
  (void)in_sizes; (void)n_in; (void)ws_size;

  k_init<<<1024, 256, 0, stream>>>((float4*)Hout);
  k_compact<<<1, 1024, 0, stream>>>(scores, sel, nsel);
  k_gemm<true ><<<dim3(64, 32), 256, 0, stream>>>(keys, W_ih, b_ih, b_hh, Gin, sel, nsel, GJ);
  k_lstm<<<NW, 512, 0, stream>>>(Gin, Hout, W_hh, nsel);
  k_gemm<false><<<dim3(64, 8), 256, 0, stream>>>(Hout, W_out, b_out, nullptr, memo, nullptr, nsel, EDIM);
  k_norms<<<576, 256, 0, stream>>>(memo, qe, dens, nsel);
  k_retrieve<<<64, 256, 0, stream>>>(memo, qe, dens, values, sel, nsel, out, top_k);
}

// Round 13
// 1825.302 us; speedup vs baseline: 1.9979x; 1.1764x over previous
//
#include <hip/hip_runtime.h>
#include <math.h>

#define SENT 2.0f
#define NTOK 2048
#define EDIM 512
#define GJ   2048   // 4*HID
#define NW   32     // worker WGs
#define HPW  16     // hidden units per WG
#define LOG2E 1.4426950408889634f

typedef float f32x4 __attribute__((ext_vector_type(4)));

__device__ __forceinline__ float sigm_f(float x) {
  return __builtin_amdgcn_rcpf(1.f + __builtin_amdgcn_exp2f(-LOG2E * x));
}
__device__ __forceinline__ float tanh_f(float x) {
  return 1.f - 2.f * __builtin_amdgcn_rcpf(1.f + __builtin_amdgcn_exp2f(2.f * LOG2E * x));
}

// ---------------- k_init: sentinel fill ----------------
__global__ __launch_bounds__(256) void k_init(float4* __restrict__ H4) {
  int i = blockIdx.x * blockDim.x + threadIdx.x;   // 262144 float4 = 2048*512 floats
  H4[i] = make_float4(SENT, SENT, SENT, SENT);
}

// ---------------- k_compact: stable compaction of selected tokens ----------------
__global__ __launch_bounds__(1024) void k_compact(const float* __restrict__ scores,
                                                  int* __restrict__ sel,
                                                  int* __restrict__ nselp) {
  __shared__ int cnt[1024];
  const int tid = threadIdx.x;
  const int i0 = tid * 2, i1 = tid * 2 + 1;
  const int m0 = (scores[i0] > 0.5f) ? 1 : 0;
  const int m1 = (scores[i1] > 0.5f) ? 1 : 0;
  cnt[tid] = m0 + m1;
  __syncthreads();
  for (int off = 1; off < 1024; off <<= 1) {
    int v = cnt[tid];
    int u = (tid >= off) ? cnt[tid - off] : 0;
    __syncthreads();
    cnt[tid] = v + u;
    __syncthreads();
  }
  int excl = (tid == 0) ? 0 : cnt[tid - 1];
  if (m0) sel[excl] = i0;
  if (m1) sel[excl + m0] = i1;
  if (tid == 1023) *nselp = cnt[1023];
}

// ---------------- k_gemm: C[t][j] = bias1[j](+bias2[j]) + sum_e Arow(t)[e]*B[j][e] ----------------
template<bool GATHER>
__global__ __launch_bounds__(256) void k_gemm(
    const float* __restrict__ A, const float* __restrict__ B,
    const float* __restrict__ bias1, const float* __restrict__ bias2,
    float* __restrict__ C, const int* __restrict__ sel,
    const int* __restrict__ nselp, int J)
{
  const int n_sel = *nselp;
  const int t0 = blockIdx.x * 32;
  if (t0 >= n_sel) return;
  const int j0 = blockIdx.y * 64;
  const int tid = threadIdx.x;
  __shared__ float As[32][36];
  __shared__ float Bst[32][68];
  __shared__ int rowsrc[32];
  if (tid < 32) {
    int t = t0 + tid;
    int r = -1;
    if (t < n_sel) r = GATHER ? sel[t] : t;
    rowsrc[tid] = r;
  }
  __syncthreads();
  const int tx = tid & 15;
  const int ty = tid >> 4;
  float4 acc0 = make_float4(0.f, 0.f, 0.f, 0.f);
  float4 acc1 = make_float4(0.f, 0.f, 0.f, 0.f);
  for (int e0 = 0; e0 < EDIM; e0 += 32) {
    {
      int t = tid >> 3, e4 = tid & 7;
      int r = rowsrc[t];
      float4 v = make_float4(0.f, 0.f, 0.f, 0.f);
      if (r >= 0) v = ((const float4*)(A + (size_t)r * EDIM + e0))[e4];
      *(float4*)&As[t][e4 * 4] = v;
    }
    #pragma unroll
    for (int l = 0; l < 2; ++l) {
      int idx = tid + l * 256;
      int j = idx >> 3, e4 = idx & 7;
      float4 v = ((const float4*)(B + (size_t)(j0 + j) * EDIM + e0))[e4];
      Bst[e4 * 4 + 0][j] = v.x; Bst[e4 * 4 + 1][j] = v.y;
      Bst[e4 * 4 + 2][j] = v.z; Bst[e4 * 4 + 3][j] = v.w;
    }
    __syncthreads();
    #pragma unroll
    for (int e = 0; e < 32; ++e) {
      float a0 = As[ty * 2 + 0][e];
      float a1 = As[ty * 2 + 1][e];
      float4 b = *(const float4*)&Bst[e][tx * 4];
      acc0.x += a0 * b.x; acc0.y += a0 * b.y; acc0.z += a0 * b.z; acc0.w += a0 * b.w;
      acc1.x += a1 * b.x; acc1.y += a1 * b.y; acc1.z += a1 * b.z; acc1.w += a1 * b.w;
    }
    __syncthreads();
  }
  float4 bv = ((const float4*)bias1)[(j0 >> 2) + tx];
  if (bias2) {
    float4 b2 = ((const float4*)bias2)[(j0 >> 2) + tx];
    bv.x += b2.x; bv.y += b2.y; bv.z += b2.z; bv.w += b2.w;
  }
  #pragma unroll
  for (int i = 0; i < 2; ++i) {
    int t = t0 + ty * 2 + i;
    if (t < n_sel) {
      float4 a = (i == 0) ? acc0 : acc1;
      float4 r = make_float4(a.x + bv.x, a.y + bv.y, a.z + bv.z, a.w + bv.w);
      *(float4*)(C + (size_t)t * J + j0 + tx * 4) = r;
    }
  }
}

// ---------------- k_lstm: persistent recurrence, single barrier/step (r7 champion) ----------------
// 32 WGs x 512 threads, 1/CU. WG w owns units [w*16, w*16+16).
// Row map: row_local = tid>>3, gate g = row&3, unit jl = row>>2 -> unit u's 4 gate
// rows = tids [32u, 32u+32) = one wave half; after xor-reduce, 3 shuffles hand
// f/g/o sums to gate lane (tid%32==0). No gsum LDS, no second barrier.
// hbuf[2][512] parity: pollers fill hbuf[t&1] pre-barrier; gates fill hbuf[t&1^1]
// post-dot -> no read/write overlap with ONE __syncthreads per step.
// Poll: 2-deep pipelined (4 dword loads per batch, vmcnt(4) checks older batch).
// NOTE (r12 falsification): the Gin prefetch BEFORE the poll is load-bearing —
// its vmcnt drain delays the first sentinel check to ~when the producer's h
// becomes L3-visible. Polling earlier (r12) or from dedicated waves (r11) only
// adds L3 contention that slows the producer's own store. Do not reorder.
__global__ __launch_bounds__(512, 1) void k_lstm(
    const float* __restrict__ Gin, float* __restrict__ Hout,
    const float* __restrict__ Whh, const int* __restrict__ nselp)
{
  const int tid = threadIdx.x;
  const int n_sel = *nselp;
  if (n_sel <= 0) return;
  const int w = blockIdx.x;

  const int row_local = tid >> 3;        // 0..63
  const int sub = tid & 7;
  const int g = row_local & 3;           // gate 0..3 (i,f,g,o)
  const int jl = row_local >> 2;         // unit within slice
  const int grow = g * 512 + w * HPW + jl;
  const int c0 = sub * 64;
  float4 wv[16];
  {
    const float4* wp = (const float4*)(Whh + (size_t)grow * 512 + c0);
    #pragma unroll
    for (int k = 0; k < 16; ++k) wv[k] = wp[(k + sub) & 15];
  }

  // roles
  const bool gatel = (tid & 31) == 0;            // gate lane, unit u
  const int u = tid >> 5;
  const bool pol = (tid & 1) && (tid < 256);     // pollers: odd tids, waves 0-3
  const int q = pol ? ((tid - 1) >> 1) : -1;     // quad 0..127
  const bool pact = pol && (q < 4 * w || q >= 4 * w + 4);

  __shared__ float hbuf[2][512];
  hbuf[0][tid] = 0.f;                            // h(-1) = 0 (barrier in iter 0 orders)
  float cst = 0.f;
  float gx0 = 0.f, gx1 = 0.f, gx2 = 0.f, gx3 = 0.f;
  if (gatel) {
    const float* gr = Gin + w * HPW + u;
    gx0 = gr[0]; gx1 = gr[512]; gx2 = gr[1024]; gx3 = gr[1536];
  }
  for (int t = 0; t < n_sel; ++t) {
    const int cur = t & 1;
    float nx0 = 0.f, nx1 = 0.f, nx2 = 0.f, nx3 = 0.f;
    if (gatel && t + 1 < n_sel) {
      const float* gr = Gin + (size_t)(t + 1) * GJ + w * HPW + u;
      nx0 = gr[0]; nx1 = gr[512]; nx2 = gr[1024]; nx3 = gr[1536];
    }
    if (t > 0 && pact) {
      const float* src = Hout + (size_t)(t - 1) * 512 + q * 4;
      float a0, a1, a2, a3, b0, b1, b2, b3, m;
      // 2-deep pipelined sentinel poll: monotone (SENT->value) data makes
      // wave-uniform looping safe; drain vmcnt before buffers are reused.
      asm volatile(
        "global_load_dword %[a0], %[s], off sc0 sc1\n\t"
        "global_load_dword %[a1], %[s], off offset:4 sc0 sc1\n\t"
        "global_load_dword %[a2], %[s], off offset:8 sc0 sc1\n\t"
        "global_load_dword %[a3], %[s], off offset:12 sc0 sc1\n\t"
        "global_load_dword %[b0], %[s], off sc0 sc1\n\t"
        "global_load_dword %[b1], %[s], off offset:4 sc0 sc1\n\t"
        "global_load_dword %[b2], %[s], off offset:8 sc0 sc1\n\t"
        "global_load_dword %[b3], %[s], off offset:12 sc0 sc1\n\t"
        "PL%=:\n\t"
        "s_waitcnt vmcnt(4)\n\t"                      // batch A landed
        "v_max3_f32 %[m], %[a0], %[a1], %[a2]\n\t"
        "v_max_f32 %[m], %[m], %[a3]\n\t"
        "v_cmp_lt_f32 vcc, 1.5, %[m]\n\t"             // lane still-sentinel?
        "s_cbranch_vccz GA%=\n\t"                     // all lanes got -> A valid
        "global_load_dword %[a0], %[s], off sc0 sc1\n\t"
        "global_load_dword %[a1], %[s], off offset:4 sc0 sc1\n\t"
        "global_load_dword %[a2], %[s], off offset:8 sc0 sc1\n\t"
        "global_load_dword %[a3], %[s], off offset:12 sc0 sc1\n\t"
        "s_waitcnt vmcnt(4)\n\t"                      // batch B landed
        "v_max3_f32 %[m], %[b0], %[b1], %[b2]\n\t"
        "v_max_f32 %[m], %[m], %[b3]\n\t"
        "v_cmp_lt_f32 vcc, 1.5, %[m]\n\t"
        "s_cbranch_vccz GB%=\n\t"
        "global_load_dword %[b0], %[s], off sc0 sc1\n\t"
        "global_load_dword %[b1], %[s], off offset:4 sc0 sc1\n\t"
        "global_load_dword %[b2], %[s], off offset:8 sc0 sc1\n\t"
        "global_load_dword %[b3], %[s], off offset:12 sc0 sc1\n\t"
        "s_branch PL%=\n\t"
        "GB%=:\n\t"
        "s_waitcnt vmcnt(0)\n\t"                      // in-flight A lands (stale) first
        "v_mov_b32 %[a0], %[b0]\n\t"
        "v_mov_b32 %[a1], %[b1]\n\t"
        "v_mov_b32 %[a2], %[b2]\n\t"
        "v_mov_b32 %[a3], %[b3]\n\t"
        "GA%=:\n\t"
        "s_waitcnt vmcnt(0)\n\t"                      // drain leftover B (discard)
        : [a0]"=&v"(a0), [a1]"=&v"(a1), [a2]"=&v"(a2), [a3]"=&v"(a3),
          [b0]"=&v"(b0), [b1]"=&v"(b1), [b2]"=&v"(b2), [b3]"=&v"(b3),
          [m]"=&v"(m)
        : [s]"v"(src)
        : "vcc", "memory");
      hbuf[cur][q * 4 + 0] = a0; hbuf[cur][q * 4 + 1] = a1;
      hbuf[cur][q * 4 + 2] = a2; hbuf[cur][q * 4 + 3] = a3;
    }
    __syncthreads();   // the ONLY barrier per step
    // partial dot over 64 cols, sub-rotated, 4 accumulators
    const float4* hv = (const float4*)&hbuf[cur][c0];
    float s0 = 0.f, s1 = 0.f, s2 = 0.f, s3 = 0.f;
    #pragma unroll
    for (int k = 0; k < 4; ++k) {
      float4 w4, h4;
      w4 = wv[4*k+0]; h4 = hv[(4*k+0+sub)&15]; s0 += w4.x*h4.x + w4.y*h4.y + w4.z*h4.z + w4.w*h4.w;
      w4 = wv[4*k+1]; h4 = hv[(4*k+1+sub)&15]; s1 += w4.x*h4.x + w4.y*h4.y + w4.z*h4.z + w4.w*h4.w;
      w4 = wv[4*k+2]; h4 = hv[(4*k+2+sub)&15]; s2 += w4.x*h4.x + w4.y*h4.y + w4.z*h4.z + w4.w*h4.w;
      w4 = wv[4*k+3]; h4 = hv[(4*k+3+sub)&15]; s3 += w4.x*h4.x + w4.y*h4.y + w4.z*h4.z + w4.w*h4.w;
    }
    float s = (s0 + s1) + (s2 + s3);
    s += __shfl_xor(s, 1); s += __shfl_xor(s, 2); s += __shfl_xor(s, 4);
    // hand f/g/o row sums to the gate lane of each unit (same wave by construction)
    const int lane = tid & 63;
    float sf = __shfl(s, lane + 8);
    float sg = __shfl(s, lane + 16);
    float so = __shfl(s, lane + 24);
    if (gatel) {
      float gi = gx0 + s;
      float gf = gx1 + sf;
      float gg = gx2 + sg;
      float go = gx3 + so;
      float ig = sigm_f(gi);
      float fg = sigm_f(gf);
      float og = sigm_f(go);
      cst = fg * cst + ig * tanh_f(gg);
      float h = og * tanh_f(cst);   // in (-1,1): sentinel 2.0f unreachable
      __hip_atomic_store(Hout + (size_t)t * 512 + w * HPW + u, h,
                         __ATOMIC_RELAXED, __HIP_MEMORY_SCOPE_AGENT);
      hbuf[cur ^ 1][w * HPW + u] = h;   // next step's buffer: no reader overlap
      gx0 = nx0; gx1 = nx1; gx2 = nx2; gx3 = nx3;
    }
  }
}

// ---------------- k_norms: row L2 norms (memory keys + queries) ----------------
__global__ __launch_bounds__(256) void k_norms(
    const float* __restrict__ memo, const float* __restrict__ qe,
    float* __restrict__ dens, const int* __restrict__ nselp)
{
  const int n_sel = *nselp;
  const int row = blockIdx.x * 4 + (threadIdx.x >> 6);
  const int lane = threadIdx.x & 63;
  const float* src;
  if (row < NTOK) {
    if (row >= n_sel) return;
    src = memo + (size_t)row * EDIM;
  } else {
    if (row >= NTOK + 256) return;
    src = qe + (size_t)(row - NTOK) * EDIM;
  }
  const float4* s4 = (const float4*)src;
  float4 a = s4[lane], b = s4[lane + 64];
  float s = a.x*a.x + a.y*a.y + a.z*a.z + a.w*a.w
          + b.x*b.x + b.y*b.y + b.z*b.z + b.w*b.w;
  #pragma unroll
  for (int off = 32; off; off >>= 1) s += __shfl_xor(s, off);
  if (lane == 0) dens[row] = fmaxf(sqrtf(s), 1e-12f);
}

// ---------------- k_retrieve: sims + top-k + gather (4 queries per block) ----------------
__global__ __launch_bounds__(256) void k_retrieve(
    const float* __restrict__ memo, const float* __restrict__ qe,
    const float* __restrict__ dens, const float* __restrict__ values,
    const int* __restrict__ sel, const int* __restrict__ nselp,
    float* __restrict__ out, int top_k)
{
  const int n_sel = *nselp;
  const int qb = blockIdx.x * 4;
  const int tid = threadIdx.x;
  __shared__ float qs[4][EDIM];
  __shared__ float sims[4][NTOK];
  __shared__ int tix[4][8];
  for (int l = tid; l < 512; l += 256) {
    int q = l >> 7, e4 = l & 127;
    float4 v = ((const float4*)(qe + (size_t)(qb + q) * EDIM))[e4];
    float inv = 1.f / dens[NTOK + qb + q];
    v.x *= inv; v.y *= inv; v.z *= inv; v.w *= inv;
    *(float4*)&qs[q][e4 * 4] = v;
  }
  __syncthreads();
  for (int t = tid; t < n_sel; t += 256) {
    const float4* m4 = (const float4*)(memo + (size_t)t * EDIM);
    float a0 = 0.f, a1 = 0.f, a2 = 0.f, a3 = 0.f;
    for (int e4 = 0; e4 < 128; ++e4) {
      float4 m = m4[e4];
      float4 q0 = *(const float4*)&qs[0][e4 * 4];
      float4 q1 = *(const float4*)&qs[1][e4 * 4];
      float4 q2 = *(const float4*)&qs[2][e4 * 4];
      float4 q3 = *(const float4*)&qs[3][e4 * 4];
      a0 += m.x*q0.x + m.y*q0.y + m.z*q0.z + m.w*q0.w;
      a1 += m.x*q1.x + m.y*q1.y + m.z*q1.z + m.w*q1.w;
      a2 += m.x*q2.x + m.y*q2.y + m.z*q2.z + m.w*q2.w;
      a3 += m.x*q3.x + m.y*q3.y + m.z*q3.z + m.w*q3.w;
    }
    float inv = 1.f / dens[t];
    sims[0][t] = a0 * inv; sims[1][t] = a1 * inv;
    sims[2][t] = a2 * inv; sims[3][t] = a3 * inv;
  }
  __syncthreads();
  const int wq = tid >> 6, lane = tid & 63;
  for (int r = 0; r < top_k; ++r) {
    if (r < n_sel) {
      float bv = -INFINITY; int bi = 0x7fffffff;
      for (int t = lane; t < n_sel; t += 64) {
        float v = sims[wq][t];
        if (v > bv || (v == bv && t < bi)) { bv = v; bi = t; }
      }
      #pragma unroll
      for (int off = 32; off; off >>= 1) {
        float ov = __shfl_xor(bv, off);
        int   oi = __shfl_xor(bi, off);
        if (ov > bv || (ov == bv && oi < bi)) { bv = ov; bi = oi; }
      }
      if (lane == 0) { tix[wq][r] = bi; sims[wq][bi] = -INFINITY; }
    } else if (lane == 0) {
      tix[wq][r] = -1;
    }
    __syncthreads();
  }
  const int tot = 4 * top_k * 128;
  for (int l = tid; l < tot; l += 256) {
    int q = l / (top_k * 128);
    int rem = l - q * top_k * 128;
    int r = rem >> 7;
    int e4 = rem & 127;
    int t = tix[q][r];
    float4 v = make_float4(0.f, 0.f, 0.f, 0.f);
    if (t >= 0) v = ((const float4*)(values + (size_t)sel[t] * EDIM))[e4];
    ((float4*)out)[(((size_t)(qb + q) * top_k) + r) * 128 + e4] = v;
  }
}

extern "C" void kernel_launch(void* const* d_in, const int* in_sizes, int n_in,
                              void* d_out, int out_size, void* d_ws, size_t ws_size,
                              hipStream_t stream) {
  const float* keys   = (const float*)d_in[0];
  const float* values = (const float*)d_in[1];
  const float* scores = (const float*)d_in[2];
  const float* qe     = (const float*)d_in[3];
  const float* W_ih   = (const float*)d_in[6];
  const float* W_hh   = (const float*)d_in[7];
  const float* b_ih   = (const float*)d_in[8];
  const float* b_hh   = (const float*)d_in[9];
  const float* W_out  = (const float*)d_in[10];
  const float* b_out  = (const float*)d_in[11];
  float* out = (float*)d_out;
  const int top_k = out_size / (256 * 512);   // = 8

  char* ws = (char*)d_ws;
  int*   nsel   = (int*)ws;                             // 4 B
  int*   sel    = (int*)(ws + 4096);                    // 8 KB
  float* dens   = (float*)(ws + 16384);                 // 9 KB
  float* Hout   = (float*)(ws + (size_t)(1u << 20));    // 4 MB  [1M,5M)
  float* Gin    = (float*)(ws + (size_t)(9u << 20));    // 16 MB [9M,25M)
  float* memo   = (float*)(ws + (size_t)(9u << 20));    // 4 MB, aliases Gin (dead by then)
  (void)in_sizes; (void)n_in; (void)ws_size;

  k_init<<<1024, 256, 0, stream>>>((float4*)Hout);
  k_compact<<<1, 1024, 0, stream>>>(scores, sel, nsel);
  k_gemm<true ><<<dim3(64, 32), 256, 0, stream>>>(keys, W_ih, b_ih, b_hh, Gin, sel, nsel, GJ);
  k_lstm<<<NW, 512, 0, stream>>>(Gin, Hout, W_hh, nsel);
  k_gemm<false><<<dim3(64, 8), 256, 0, stream>>>(Hout, W_out, b_out, nullptr, memo, nullptr, nsel, EDIM);
  k_norms<<<576, 256, 0, stream>>>(memo, qe, dens, nsel);
  k_retrieve<<<64, 256, 0, stream>>>(memo, qe, dens, values, sel, nsel, out, top_k);
}